// Round 2
// baseline (102.533 us; speedup 1.0000x reference)
//
#include <hip/hip_runtime.h>

#define S_DEPTH 128
#define N_RES   512
#define E_DIM   256
#define P_DIM   32
#define C_DIM   128

typedef short bh8 __attribute__((ext_vector_type(8)));   // 8 x bf16 (raw shorts)
typedef float fx4 __attribute__((ext_vector_type(4)));   // MFMA f32 accumulator

__device__ __forceinline__ unsigned short f2bf(float x){
    unsigned int u = __builtin_bit_cast(unsigned int, x);
    u += 0x7fffu + ((u >> 16) & 1u);          // round-to-nearest-even
    return (unsigned short)(u >> 16);
}

// ---------------------------------------------------------------------------
// K0: transpose weights to bf16. 48 blocks x 256 = 12288 threads = 8192+4096.
//   WaT/WbT: [P][E]  (E contiguous)   WpT: [C][P]  (P contiguous)
// ---------------------------------------------------------------------------
__global__ void prep_kernel(const float* __restrict__ Wa, const float* __restrict__ Wb,
                            const float* __restrict__ Wp,
                            unsigned short* __restrict__ WaT, unsigned short* __restrict__ WbT,
                            unsigned short* __restrict__ WpT){
    int tid = blockIdx.x * 256 + threadIdx.x;
    if (tid < 8192){
        int p = tid >> 8, e = tid & 255;
        WaT[tid] = f2bf(Wa[e * P_DIM + p]);
        WbT[tid] = f2bf(Wb[e * P_DIM + p]);
    } else {
        int i = tid - 8192;
        int c = i >> 5, p = i & 31;
        WpT[i] = f2bf(Wp[p * C_DIM + c]);
    }
}

// ---------------------------------------------------------------------------
// K1: LayerNorm + dual projection. Grid (512 n, 2 s-halves), 256 thr, 32 KB LDS.
//   Phase 1: LN of 64 rows -> bf16 swizzled LDS.
//   Phase 2: D[s][p] = xn(s,k) @ W(k,p) via MFMA (A = x-frag, B = W-frag).
//   Epilogue: 8-B packed stores of 4 consecutive s into aT/bT [p][n][s].
// ---------------------------------------------------------------------------
__global__ __launch_bounds__(256, 4) void lnproj_kernel(
    const float* __restrict__ x, const float* __restrict__ gamma, const float* __restrict__ beta,
    const unsigned short* __restrict__ WaT, const unsigned short* __restrict__ WbT,
    const float* __restrict__ ba, const float* __restrict__ bb,
    unsigned short* __restrict__ aT, unsigned short* __restrict__ bT)
{
    __shared__ __align__(16) char smem[64 * 512];      // 64 s-rows x 512 B = 32 KB
    const int n0   = blockIdx.x;
    const int sh   = blockIdx.y;                       // s-half (0/1)
    const int tid  = threadIdx.x;
    const int lane = tid & 63;
    const int w    = tid >> 6;                         // 4 waves
    const int l15  = lane & 15;
    const int lq   = lane >> 4;

    const float4 g4 = *(const float4*)(gamma + lane * 4);
    const float4 b4 = *(const float4*)(beta  + lane * 4);

    // ---- phase 1: LN, 16 rows per wave ----
    for (int rr = 0; rr < 16; ++rr){
        int s_loc = w * 16 + rr;
        int s     = sh * 64 + s_loc;
        float4 v = *(const float4*)(x + ((size_t)(s * N_RES + n0)) * E_DIM + lane * 4);
        float sum = v.x + v.y + v.z + v.w;
        float sq  = v.x*v.x + v.y*v.y + v.z*v.z + v.w*v.w;
        #pragma unroll
        for (int m = 1; m < 64; m <<= 1){
            sum += __shfl_xor(sum, m);
            sq  += __shfl_xor(sq,  m);
        }
        float mu  = sum * (1.0f / E_DIM);
        float inv = rsqrtf(sq * (1.0f / E_DIM) - mu * mu + 1e-5f);
        ushort4 pk;
        pk.x = f2bf((v.x - mu) * inv * g4.x + b4.x);
        pk.y = f2bf((v.y - mu) * inv * g4.y + b4.y);
        pk.z = f2bf((v.z - mu) * inv * g4.z + b4.z);
        pk.w = f2bf((v.w - mu) * inv * g4.w + b4.w);
        int boff = s_loc * 512 + lane * 8;
        boff ^= (s_loc & 7) << 4;                      // 16-B-granule XOR swizzle
        *(ushort4*)(smem + boff) = pk;
    }
    __syncthreads();

    // ---- phase 2: wave w owns s-tile w (16 s-rows). D[s][p]. ----
    fx4 accA[2], accB[2];                              // [pt]
    #pragma unroll
    for (int pt = 0; pt < 2; ++pt){
        accA[pt] = fx4{0.f, 0.f, 0.f, 0.f};
        accB[pt] = fx4{0.f, 0.f, 0.f, 0.f};
    }
    const int srow = w * 16 + l15;

    #pragma unroll
    for (int ks = 0; ks < 8; ++ks){                    // K = 256 = 8 x 32
        int boff = srow * 512 + (ks * 32 + lq * 8) * 2;
        boff ^= (srow & 7) << 4;
        bh8 xf = *(const bh8*)(smem + boff);           // A: row s, 8 contig k
        #pragma unroll
        for (int pt = 0; pt < 2; ++pt){
            int off = (pt * 16 + l15) * E_DIM + ks * 32 + lq * 8;   // B: col p
            bh8 wa = *(const bh8*)(WaT + off);
            bh8 wb = *(const bh8*)(WbT + off);
            accA[pt] = __builtin_amdgcn_mfma_f32_16x16x32_bf16(xf, wa, accA[pt], 0, 0, 0);
            accB[pt] = __builtin_amdgcn_mfma_f32_16x16x32_bf16(xf, wb, accB[pt], 0, 0, 0);
        }
    }

    // ---- epilogue: D col = p (l15), row = s (lq*4+j) -> packed 8-B stores ----
    #pragma unroll
    for (int pt = 0; pt < 2; ++pt){
        int p = pt * 16 + l15;
        float bav = ba[p], bbv = bb[p];
        int s_base = sh * 64 + w * 16 + lq * 4;
        size_t o = ((size_t)p * N_RES + n0) * S_DEPTH + s_base;
        ushort4 ua, ub;
        ua.x = f2bf(accA[pt][0] + bav); ua.y = f2bf(accA[pt][1] + bav);
        ua.z = f2bf(accA[pt][2] + bav); ua.w = f2bf(accA[pt][3] + bav);
        ub.x = f2bf(accB[pt][0] + bbv); ub.y = f2bf(accB[pt][1] + bbv);
        ub.z = f2bf(accB[pt][2] + bbv); ub.w = f2bf(accB[pt][3] + bbv);
        *(ushort4*)(aT + o) = ua;
        *(ushort4*)(bT + o) = ub;
    }
}

// ---------------------------------------------------------------------------
// K2: fused batched outer (mean over S) + Wp projection + bias.
//   512 blocks (16 tn x 32 tm), 32x16 nm tile, 256 thr (4 waves), 40 KB LDS.
//   Wave w owns p = 8w..8w+7; all 8 p-accs live -> b128 packed LDS writes.
//   LDS rows padded to 80 B to spread banks. XCD-swizzled blockIdx.
// ---------------------------------------------------------------------------
__global__ __launch_bounds__(256, 2) void outer_kernel(
    const unsigned short* __restrict__ aT, const unsigned short* __restrict__ bT,
    const unsigned short* __restrict__ WpT, const float* __restrict__ bp,
    float* __restrict__ out)
{
    __shared__ __align__(16) char smem[512 * 80];      // [nm=512][40 shorts, 32 used]
    int bid = blockIdx.x;
    int swz = (bid & 7) * 64 + (bid >> 3);             // XCD-contiguous chunks (512%8==0)
    const int tn = swz >> 5, tm = swz & 31;
    const int n0 = tn * 32, m0 = tm * 16;
    const int tid  = threadIdx.x;
    const int lane = tid & 63;
    const int w    = tid >> 6;                         // 4 waves
    const int l15  = lane & 15;
    const int lq   = lane >> 4;

    // ---- stage 1: outer products, 8 p per wave, all accs live ----
    fx4 acc[8][2];                                     // [q][ti]
    #pragma unroll
    for (int q = 0; q < 8; ++q)
        #pragma unroll
        for (int ti = 0; ti < 2; ++ti)
            acc[q][ti] = fx4{0.f, 0.f, 0.f, 0.f};

    #pragma unroll
    for (int ks = 0; ks < 4; ++ks){                    // K = S = 128 = 4 x 32
        #pragma unroll
        for (int q = 0; q < 8; ++q){
            int p = w * 8 + q;
            size_t kbase = (size_t)p * N_RES * S_DEPTH + ks * 32 + lq * 8;
            bh8 bfv = *(const bh8*)(bT + kbase + (size_t)(m0 + l15) * S_DEPTH);
            bh8 af0 = *(const bh8*)(aT + kbase + (size_t)(n0 + l15) * S_DEPTH);
            bh8 af1 = *(const bh8*)(aT + kbase + (size_t)(n0 + 16 + l15) * S_DEPTH);
            acc[q][0] = __builtin_amdgcn_mfma_f32_16x16x32_bf16(af0, bfv, acc[q][0], 0, 0, 0);
            acc[q][1] = __builtin_amdgcn_mfma_f32_16x16x32_bf16(af1, bfv, acc[q][1], 0, 0, 0);
        }
    }

    // ---- stage 1b: pack 8 p per lane -> one b128 LDS write per (ti,j) ----
    #pragma unroll
    for (int ti = 0; ti < 2; ++ti)
        #pragma unroll
        for (int j = 0; j < 4; ++j){
            int nm = (ti * 16 + lq * 4 + j) * 16 + l15;    // nloc*16 + mloc
            bh8 v;
            #pragma unroll
            for (int q = 0; q < 8; ++q)
                v[q] = (short)f2bf(acc[q][ti][j] * (1.0f / S_DEPTH));
            *(bh8*)(smem + nm * 80 + w * 16) = v;
        }
    __syncthreads();

    // ---- stage 2: project P -> C, fused bias, nontemporal f32 stores ----
    bh8   wpf[8];
    float bpv[8];
    #pragma unroll
    for (int ct = 0; ct < 8; ++ct){
        wpf[ct] = *(const bh8*)(WpT + (ct * 16 + l15) * P_DIM + lq * 8);  // B: col c
        bpv[ct] = bp[ct * 16 + l15];
    }
    #pragma unroll
    for (int mi = 0; mi < 8; ++mi){
        int mt = w * 8 + mi;                           // 32 mt tiles / 4 waves
        bh8 of = *(const bh8*)(smem + (mt * 16 + l15) * 80 + lq * 16);    // A: row nm, k=p
        #pragma unroll
        for (int ct = 0; ct < 8; ++ct){
            fx4 d = __builtin_amdgcn_mfma_f32_16x16x32_bf16(
                        of, wpf[ct], fx4{0.f, 0.f, 0.f, 0.f}, 0, 0, 0);
            // D row r=lq*4+j -> nm = mt*16+r -> n = n0+mt, m = m0+r; col c = ct*16+l15
            float* po = out + (((size_t)(n0 + mt) * N_RES) + m0) * C_DIM + ct * 16 + l15;
            #pragma unroll
            for (int j = 0; j < 4; ++j)
                __builtin_nontemporal_store(d[j] + bpv[ct], po + (size_t)(lq * 4 + j) * C_DIM);
        }
    }
}

// ---------------------------------------------------------------------------
extern "C" void kernel_launch(void* const* d_in, const int* in_sizes, int n_in,
                              void* d_out, int out_size, void* d_ws, size_t ws_size,
                              hipStream_t stream){
    const float* msa   = (const float*)d_in[0];
    const float* gamma = (const float*)d_in[1];
    const float* beta  = (const float*)d_in[2];
    const float* Wa    = (const float*)d_in[3];
    const float* ba    = (const float*)d_in[4];
    const float* Wb    = (const float*)d_in[5];
    const float* bb    = (const float*)d_in[6];
    const float* Wp    = (const float*)d_in[7];
    const float* bp    = (const float*)d_in[8];
    float* out = (float*)d_out;

    // workspace (ushort elems): aT | bT | WaT | WbT | WpT
    unsigned short* ws  = (unsigned short*)d_ws;
    unsigned short* aT  = ws;                        // 32*512*128 = 2097152
    unsigned short* bT  = ws + 2097152;
    unsigned short* WaT = ws + 4194304;              // 8192
    unsigned short* WbT = WaT + 8192;                // 8192
    unsigned short* WpT = WbT + 8192;                // 4096

    prep_kernel<<<48, 256, 0, stream>>>(Wa, Wb, Wp, WaT, WbT, WpT);
    lnproj_kernel<<<dim3(N_RES, 2), 256, 0, stream>>>(msa, gamma, beta, WaT, WbT, ba, bb, aT, bT);
    outer_kernel<<<512, 256, 0, stream>>>(aT, bT, WpT, bp, out);
}

// Round 3
// 76.682 us; speedup vs baseline: 1.3371x; 1.3371x over previous
//
#include <hip/hip_runtime.h>

#define S_DEPTH 128
#define N_RES   512
#define E_DIM   256
#define P_DIM   32
#define C_DIM   128

typedef short bh8 __attribute__((ext_vector_type(8)));   // 8 x bf16 (raw shorts)
typedef short sh4 __attribute__((ext_vector_type(4)));   // 4 x bf16
typedef float fx4 __attribute__((ext_vector_type(4)));   // MFMA f32 accumulator

__device__ __forceinline__ unsigned short f2bf(float x){
    unsigned int u = __builtin_bit_cast(unsigned int, x);
    u += 0x7fffu + ((u >> 16) & 1u);          // round-to-nearest-even
    return (unsigned short)(u >> 16);
}

// ---------------------------------------------------------------------------
// K0: transpose weights to bf16. 48 blocks x 256 = 12288 threads = 8192+4096.
//   WaT/WbT: [P][E]  (E contiguous)   WpT: [C][P]  (P contiguous)
// ---------------------------------------------------------------------------
__global__ void prep_kernel(const float* __restrict__ Wa, const float* __restrict__ Wb,
                            const float* __restrict__ Wp,
                            unsigned short* __restrict__ WaT, unsigned short* __restrict__ WbT,
                            unsigned short* __restrict__ WpT){
    int tid = blockIdx.x * 256 + threadIdx.x;
    if (tid < 8192){
        int p = tid >> 8, e = tid & 255;
        WaT[tid] = f2bf(Wa[e * P_DIM + p]);
        WbT[tid] = f2bf(Wb[e * P_DIM + p]);
    } else {
        int i = tid - 8192;
        int c = i >> 5, p = i & 31;
        WpT[i] = f2bf(Wp[p * C_DIM + c]);
    }
}

// ---------------------------------------------------------------------------
// K1: LayerNorm + dual projection. Grid (512 n, 2 s-halves), 256 thr, 32 KB LDS.
//   Phase 1: LN of 64 rows -> bf16 swizzled LDS.
//   Phase 2: D[s][p] = xn(s,k) @ W(k,p) via MFMA (A = x-frag, B = W-frag).
//   Epilogue: 8-B packed stores of 4 consecutive s into aT/bT [p][n][s].
// ---------------------------------------------------------------------------
__global__ __launch_bounds__(256, 4) void lnproj_kernel(
    const float* __restrict__ x, const float* __restrict__ gamma, const float* __restrict__ beta,
    const unsigned short* __restrict__ WaT, const unsigned short* __restrict__ WbT,
    const float* __restrict__ ba, const float* __restrict__ bb,
    unsigned short* __restrict__ aT, unsigned short* __restrict__ bT)
{
    __shared__ __align__(16) char smem[64 * 512];      // 64 s-rows x 512 B = 32 KB
    const int n0   = blockIdx.x;
    const int sh   = blockIdx.y;                       // s-half (0/1)
    const int tid  = threadIdx.x;
    const int lane = tid & 63;
    const int w    = tid >> 6;                         // 4 waves
    const int l15  = lane & 15;
    const int lq   = lane >> 4;

    const float4 g4 = *(const float4*)(gamma + lane * 4);
    const float4 b4 = *(const float4*)(beta  + lane * 4);

    // ---- phase 1: LN, 16 rows per wave ----
    for (int rr = 0; rr < 16; ++rr){
        int s_loc = w * 16 + rr;
        int s     = sh * 64 + s_loc;
        float4 v = *(const float4*)(x + ((size_t)(s * N_RES + n0)) * E_DIM + lane * 4);
        float sum = v.x + v.y + v.z + v.w;
        float sq  = v.x*v.x + v.y*v.y + v.z*v.z + v.w*v.w;
        #pragma unroll
        for (int m = 1; m < 64; m <<= 1){
            sum += __shfl_xor(sum, m);
            sq  += __shfl_xor(sq,  m);
        }
        float mu  = sum * (1.0f / E_DIM);
        float inv = rsqrtf(sq * (1.0f / E_DIM) - mu * mu + 1e-5f);
        ushort4 pk;
        pk.x = f2bf((v.x - mu) * inv * g4.x + b4.x);
        pk.y = f2bf((v.y - mu) * inv * g4.y + b4.y);
        pk.z = f2bf((v.z - mu) * inv * g4.z + b4.z);
        pk.w = f2bf((v.w - mu) * inv * g4.w + b4.w);
        int boff = s_loc * 512 + lane * 8;
        boff ^= (s_loc & 7) << 4;                      // 16-B-granule XOR swizzle
        *(ushort4*)(smem + boff) = pk;
    }
    __syncthreads();

    // ---- phase 2: wave w owns s-tile w (16 s-rows). D[s][p]. ----
    fx4 accA[2], accB[2];                              // [pt]
    #pragma unroll
    for (int pt = 0; pt < 2; ++pt){
        accA[pt] = fx4{0.f, 0.f, 0.f, 0.f};
        accB[pt] = fx4{0.f, 0.f, 0.f, 0.f};
    }
    const int srow = w * 16 + l15;

    #pragma unroll
    for (int ks = 0; ks < 8; ++ks){                    // K = 256 = 8 x 32
        int boff = srow * 512 + (ks * 32 + lq * 8) * 2;
        boff ^= (srow & 7) << 4;
        bh8 xf = *(const bh8*)(smem + boff);           // A: row s, 8 contig k
        #pragma unroll
        for (int pt = 0; pt < 2; ++pt){
            int off = (pt * 16 + l15) * E_DIM + ks * 32 + lq * 8;   // B: col p
            bh8 wa = *(const bh8*)(WaT + off);
            bh8 wb = *(const bh8*)(WbT + off);
            accA[pt] = __builtin_amdgcn_mfma_f32_16x16x32_bf16(xf, wa, accA[pt], 0, 0, 0);
            accB[pt] = __builtin_amdgcn_mfma_f32_16x16x32_bf16(xf, wb, accB[pt], 0, 0, 0);
        }
    }

    // ---- epilogue: D col = p (l15), row = s (lq*4+j) -> packed 8-B stores ----
    #pragma unroll
    for (int pt = 0; pt < 2; ++pt){
        int p = pt * 16 + l15;
        float bav = ba[p], bbv = bb[p];
        int s_base = sh * 64 + w * 16 + lq * 4;
        size_t o = ((size_t)p * N_RES + n0) * S_DEPTH + s_base;
        ushort4 ua, ub;
        ua.x = f2bf(accA[pt][0] + bav); ua.y = f2bf(accA[pt][1] + bav);
        ua.z = f2bf(accA[pt][2] + bav); ua.w = f2bf(accA[pt][3] + bav);
        ub.x = f2bf(accB[pt][0] + bbv); ub.y = f2bf(accB[pt][1] + bbv);
        ub.z = f2bf(accB[pt][2] + bbv); ub.w = f2bf(accB[pt][3] + bbv);
        *(ushort4*)(aT + o) = ua;
        *(ushort4*)(bT + o) = ub;
    }
}

// ---------------------------------------------------------------------------
// K2: fused batched outer (mean over S) + Wp projection + bias.
//   256 blocks (16 tn x 16 tm), 32x32 nm tile, 512 thr (8 waves), 64 KB LDS.
//   Wave w owns p = 4w..4w+3; all 4 p-accs live -> b64 packed LDS writes with
//   an 8-B-granule XOR swizzle (4-way instead of 32-way bank conflicts).
// ---------------------------------------------------------------------------
__global__ __launch_bounds__(512, 4) void outer_kernel(
    const unsigned short* __restrict__ aT, const unsigned short* __restrict__ bT,
    const unsigned short* __restrict__ WpT, const float* __restrict__ bp,
    float* __restrict__ out)
{
    __shared__ __align__(16) char smem[1024 * 64];     // [nm=1024][32 p x 2B], swizzled
    const int tn = blockIdx.x >> 4, tm = blockIdx.x & 15;
    const int n0 = tn * 32, m0 = tm * 32;
    const int tid  = threadIdx.x;
    const int lane = tid & 63;
    const int w    = tid >> 6;                         // 8 waves
    const int l15  = lane & 15;
    const int lq   = lane >> 4;

    // ---- stage 1: outer products, 4 p per wave, all accs live ----
    fx4 acc[4][2][2];                                  // [q][ti(n)][tj(m)]
    #pragma unroll
    for (int q = 0; q < 4; ++q)
        #pragma unroll
        for (int ti = 0; ti < 2; ++ti)
            #pragma unroll
            for (int tj = 0; tj < 2; ++tj)
                acc[q][ti][tj] = fx4{0.f, 0.f, 0.f, 0.f};

    #pragma unroll
    for (int ks = 0; ks < 4; ++ks){                    // K = S = 128 = 4 x 32
        #pragma unroll
        for (int q = 0; q < 4; ++q){
            int p = w * 4 + q;
            size_t kbase = (size_t)p * N_RES * S_DEPTH + ks * 32 + lq * 8;
            bh8 af[2], bfv[2];
            #pragma unroll
            for (int t = 0; t < 2; ++t){
                af[t]  = *(const bh8*)(aT + kbase + (size_t)(n0 + t * 16 + l15) * S_DEPTH);
                bfv[t] = *(const bh8*)(bT + kbase + (size_t)(m0 + t * 16 + l15) * S_DEPTH);
            }
            #pragma unroll
            for (int ti = 0; ti < 2; ++ti)
                #pragma unroll
                for (int tj = 0; tj < 2; ++tj)
                    acc[q][ti][tj] = __builtin_amdgcn_mfma_f32_16x16x32_bf16(
                                         af[ti], bfv[tj], acc[q][ti][tj], 0, 0, 0);
        }
    }

    // ---- stage 1b: pack 4 p per lane -> one b64 LDS write per (ti,tj,j) ----
    // p-group g (4 p) lives at phys slot g ^ swz(nm), swz = ((nm>>1)&3) ^ (((nm>>7)&3)<<1)
    #pragma unroll
    for (int ti = 0; ti < 2; ++ti)
        #pragma unroll
        for (int tj = 0; tj < 2; ++tj)
            #pragma unroll
            for (int j = 0; j < 4; ++j){
                int nm  = (ti * 16 + lq * 4 + j) * 32 + (tj * 16 + l15);
                int swz = ((nm >> 1) & 3) ^ (((nm >> 7) & 3) << 1);
                sh4 v;
                #pragma unroll
                for (int q = 0; q < 4; ++q)
                    v[q] = (short)f2bf(acc[q][ti][tj][j] * (1.0f / S_DEPTH));
                *(sh4*)(smem + nm * 64 + ((w ^ swz) << 3)) = v;
            }
    __syncthreads();

    // ---- stage 2: project P -> C, fused bias, f32 stores ----
    bh8   wpf[8];
    float bpv[8];
    #pragma unroll
    for (int ct = 0; ct < 8; ++ct){
        wpf[ct] = *(const bh8*)(WpT + (ct * 16 + l15) * P_DIM + lq * 8);  // B: col c, k=p
        bpv[ct] = bp[ct * 16 + l15];
    }
    #pragma unroll
    for (int mi = 0; mi < 8; ++mi){
        int mt  = w * 8 + mi;                          // 64 row-tiles / 8 waves
        int nm  = mt * 16 + l15;
        int swz = ((nm >> 1) & 3) ^ (((nm >> 7) & 3) << 1);
        sh4 lo = *(const sh4*)(smem + nm * 64 + (((2 * lq)     ^ swz) << 3));
        sh4 hi = *(const sh4*)(smem + nm * 64 + (((2 * lq + 1) ^ swz) << 3));
        bh8 of = __builtin_shufflevector(lo, hi, 0, 1, 2, 3, 4, 5, 6, 7);  // A: row nm, k=p
        #pragma unroll
        for (int ct = 0; ct < 8; ++ct){
            fx4 d = __builtin_amdgcn_mfma_f32_16x16x32_bf16(
                        of, wpf[ct], fx4{0.f, 0.f, 0.f, 0.f}, 0, 0, 0);
            #pragma unroll
            for (int j = 0; j < 4; ++j){
                int nmr = mt * 16 + lq * 4 + j;        // D row -> nm index
                int n = nmr >> 5, m = nmr & 31;
                out[(((size_t)(n0 + n) * N_RES) + m0 + m) * C_DIM + ct * 16 + l15]
                    = d[j] + bpv[ct];
            }
        }
    }
}

// ---------------------------------------------------------------------------
extern "C" void kernel_launch(void* const* d_in, const int* in_sizes, int n_in,
                              void* d_out, int out_size, void* d_ws, size_t ws_size,
                              hipStream_t stream){
    const float* msa   = (const float*)d_in[0];
    const float* gamma = (const float*)d_in[1];
    const float* beta  = (const float*)d_in[2];
    const float* Wa    = (const float*)d_in[3];
    const float* ba    = (const float*)d_in[4];
    const float* Wb    = (const float*)d_in[5];
    const float* bb    = (const float*)d_in[6];
    const float* Wp    = (const float*)d_in[7];
    const float* bp    = (const float*)d_in[8];
    float* out = (float*)d_out;

    // workspace (ushort elems): aT | bT | WaT | WbT | WpT
    unsigned short* ws  = (unsigned short*)d_ws;
    unsigned short* aT  = ws;                        // 32*512*128 = 2097152
    unsigned short* bT  = ws + 2097152;
    unsigned short* WaT = ws + 4194304;              // 8192
    unsigned short* WbT = WaT + 8192;                // 8192
    unsigned short* WpT = WbT + 8192;                // 4096

    prep_kernel<<<48, 256, 0, stream>>>(Wa, Wb, Wp, WaT, WbT, WpT);
    lnproj_kernel<<<dim3(N_RES, 2), 256, 0, stream>>>(msa, gamma, beta, WaT, WbT, ba, bb, aT, bT);
    outer_kernel<<<256, 512, 0, stream>>>(aT, bT, WpT, bp, out);
}